// Round 3
// baseline (173.049 us; speedup 1.0000x reference)
//
#include <hip/hip_runtime.h>

#define N 4096
#define D 512
#define FRAG_SH 512            // shorts per 16x32 MFMA fragment (1 KB)
#define NTHR 256
#define SC_STRIDE 136          // qk scratch row stride in shorts (272 B)
#define SMEM_BYTES 69632       // 4 waves * 64 rows * 136 shorts * 2 B
#define KS2 8                  // pv K-split (chunks)

typedef __attribute__((ext_vector_type(8))) short short8;
typedef __attribute__((ext_vector_type(4))) float f32x4;

__device__ __forceinline__ unsigned short f2bf(float f) {
    unsigned int u = __float_as_uint(f);
    u = (u + 0x7FFFu + ((u >> 16) & 1u)) >> 16;
    return (unsigned short)u;
}
__device__ __forceinline__ unsigned short f2bf_rn(float f) {
    return (unsigned short)((__float_as_uint(f) + 0x8000u) >> 16);
}
__device__ __forceinline__ float bf2f(unsigned short u) {
    return __uint_as_float((unsigned)u << 16);
}

// ---------------- prep ----------------
// blocks [0,128): Q 32-row tile -> Qblk (A-frag-linear, pre-scaled 1/sqrt(D))
// blocks [128,256): hist 32-row tile -> Kblk (B-frag) + Vblk (B-frag)
// blocks [256,258): zero dsum; blocks [258,514): zero out (8 MB)
__global__ __launch_bounds__(NTHR) void prep_kernel(
    const float* __restrict__ q, const float* __restrict__ hist,
    unsigned short* __restrict__ Qblk, unsigned short* __restrict__ Kblk,
    unsigned short* __restrict__ Vblk, float* __restrict__ dsum,
    float* __restrict__ out)
{
    __shared__ unsigned short smem[32 * 512];
    const int bid = blockIdx.x, tid = threadIdx.x;
    if (bid >= 256) {
        if (bid < 258) {
            int z = (bid - 256) * NTHR + tid;       // 0..511
            #pragma unroll
            for (int j = 0; j < 8; ++j) dsum[z * 8 + j] = 0.f;
        } else {
            // 256 blocks x 2048 float4 = 2M floats = out (N*D)
            const float4 zz = {0.f, 0.f, 0.f, 0.f};
            int base = (bid - 258) * 2048 + tid;    // float4 units
            #pragma unroll
            for (int j = 0; j < 8; ++j)
                ((float4*)out)[base + j * NTHR] = zz;
        }
        return;
    }
    const bool isQ = bid < 128;
    const int t = isQ ? bid : bid - 128;
    const float* src = isQ ? q : hist;
    const float scale = isQ ? 0.04419417382415922f : 1.0f;

    #pragma unroll
    for (int k = 0; k < 16; ++k) {
        int idx = tid + k * 256;
        int row = idx >> 7;
        int c4  = (idx & 127) << 2;
        float4 v = *(const float4*)(src + (size_t)(t * 32 + row) * D + c4);
        ushort4 o;
        o.x = f2bf(v.x * scale); o.y = f2bf(v.y * scale);
        o.z = f2bf(v.z * scale); o.w = f2bf(v.w * scale);
        *(ushort4*)(smem + row * 512 + c4) = o;
    }
    __syncthreads();

    unsigned short* ABdst = isQ ? Qblk : Kblk;
    #pragma unroll
    for (int k = 0; k < 8; ++k) {
        int s = tid + k * 256;
        int fl = s >> 6, ln = s & 63;
        int dk = fl >> 1, rbl = fl & 1;
        int l16 = ln & 15, qq = ln >> 4;
        short8 v = *(const short8*)(smem + (rbl * 16 + l16) * 512 + dk * 32 + qq * 8);
        *(short8*)(ABdst + ((size_t)dk * 256 + t * 2 + rbl) * FRAG_SH + ln * 8) = v;
    }
    if (!isQ) {
        #pragma unroll
        for (int k = 0; k < 8; ++k) {
            int s = tid + k * 256;
            int db = s >> 6, ln = s & 63;
            int l16 = ln & 15, qq = ln >> 4;
            unsigned short tmp[8];
            #pragma unroll
            for (int j = 0; j < 8; ++j)
                tmp[j] = smem[(qq * 8 + j) * 512 + db * 16 + l16];
            *(short8*)(Vblk + ((size_t)t * 32 + db) * FRAG_SH + ln * 8) = *(const short8*)tmp;
        }
    }
}

// ---------------- qk ----------------
// 512 blocks: rg = bid>>4 (128-row group), cg XCD-affine (256-col group).
// 4 waves, wave tile 64x128 (acc 4x8): 32 MFMA + 12 coalesced 1KB loads/iter,
// barrier-free; epilogue = collapsed-MLP tw*exp + row-sum atomics + C->A via
// wave-private LDS; P written frag-linear (frag = kb32*256 + rowfrag).
// setprio(1) around the MFMA cluster: independent-wave regime (m191 case).
__global__ __launch_bounds__(NTHR, 2) void qk_kernel(
    const unsigned short* __restrict__ Qblk, const unsigned short* __restrict__ Kblk,
    const float* __restrict__ times,
    const float* __restrict__ w1, const float* __restrict__ b1,
    const float* __restrict__ w2, const float* __restrict__ b2,
    unsigned short* __restrict__ Pblk, float* __restrict__ dsum)
{
    extern __shared__ unsigned short smem[];
    const int tid = threadIdx.x, bid = blockIdx.x;
    const int wv = tid >> 6, lane = tid & 63;
    const int qq = lane >> 4, l16 = lane & 15;
    const int wy = wv >> 1, wx = wv & 1;
    const int cg = ((bid & 7) << 1) | ((bid >> 3) & 1);  // XCD-affine col group
    const int rg = bid >> 4;

    f32x4 acc[4][8];
    #pragma unroll
    for (int fy = 0; fy < 4; ++fy)
        #pragma unroll
        for (int fx = 0; fx < 8; ++fx) acc[fy][fx] = (f32x4){0.f, 0.f, 0.f, 0.f};

    for (int dk = 0; dk < 16; ++dk) {
        short8 a[4], b[8];
        #pragma unroll
        for (int fy = 0; fy < 4; ++fy)
            a[fy] = *(const short8*)(Qblk + ((size_t)dk * 256 + rg * 8 + wy * 4 + fy) * FRAG_SH + lane * 8);
        #pragma unroll
        for (int fx = 0; fx < 8; ++fx)
            b[fx] = *(const short8*)(Kblk + ((size_t)dk * 256 + cg * 16 + wx * 8 + fx) * FRAG_SH + lane * 8);
        __builtin_amdgcn_s_setprio(1);
        #pragma unroll
        for (int fy = 0; fy < 4; ++fy)
            #pragma unroll
            for (int fx = 0; fx < 8; ++fx)
                acc[fy][fx] = __builtin_amdgcn_mfma_f32_16x16x32_bf16(a[fy], b[fx], acc[fy][fx], 0, 0, 0);
        __builtin_amdgcn_s_setprio(0);
    }

    float w1v[8], b1v[8], w2v[8];
    #pragma unroll
    for (int k = 0; k < 8; ++k) { w1v[k] = w1[k]; b1v[k] = b1[k]; w2v[k] = w2[k]; }
    const float b2v = b2[0];
    bool fast = true;
    #pragma unroll
    for (int k = 0; k < 8; ++k) fast = fast && (b1v[k] == 0.0f);
    float C1 = 0.0f;
    #pragma unroll
    for (int k = 0; k < 8; ++k) C1 += w2v[k] * fmaxf(w1v[k], 0.0f);

    const int rowbase = rg * 128 + wy * 64;
    const int colbase = cg * 256 + wx * 128;
    float tcol[8];
    #pragma unroll
    for (int fx = 0; fx < 8; ++fx) tcol[fx] = times[colbase + fx * 16 + l16];
    float trow[16];
    #pragma unroll
    for (int fy = 0; fy < 4; ++fy)
        #pragma unroll
        for (int ri = 0; ri < 4; ++ri)
            trow[fy * 4 + ri] = times[rowbase + fy * 16 + qq * 4 + ri];

    unsigned short* sc = smem + wv * (64 * SC_STRIDE);   // wave-private 64x136
    #pragma unroll
    for (int fy = 0; fy < 4; ++fy) {
        #pragma unroll
        for (int ri = 0; ri < 4; ++ri) {
            const float tq = trow[fy * 4 + ri];
            float se = 0.f;
            #pragma unroll
            for (int fx = 0; fx < 8; ++fx) {
                float td = fabsf(tq - tcol[fx]);
                float a = fmaf(td, C1, b2v);
                if (!fast) {
                    a = b2v;
                    #pragma unroll
                    for (int k = 0; k < 8; ++k)
                        a += w2v[k] * fmaxf(fmaf(td, w1v[k], b1v[k]), 0.f);
                }
                float twt = __builtin_amdgcn_rcpf(1.0f + __expf(-a));
                float e = __expf(acc[fy][fx][ri] * twt);   // 1/sqrt(D) folded into Q
                se += e;
                sc[(fy * 16 + qq * 4 + ri) * SC_STRIDE + fx * 16 + l16] = f2bf_rn(e);
            }
            se += __shfl_xor(se, 1);
            se += __shfl_xor(se, 2);
            se += __shfl_xor(se, 4);
            se += __shfl_xor(se, 8);
            if (l16 == 0) atomicAdd(dsum + rowbase + fy * 16 + qq * 4 + ri, se);
        }
    }
    #pragma unroll
    for (int fy = 0; fy < 4; ++fy)
        #pragma unroll
        for (int kb = 0; kb < 4; ++kb) {
            short8 v = *(const short8*)(sc + (fy * 16 + l16) * SC_STRIDE + kb * 32 + qq * 8);
            size_t fidx = (size_t)(cg * 8 + wx * 4 + kb) * 256 + (rg * 8 + wy * 4 + fy);
            *(short8*)(Pblk + fidx * FRAG_SH + lane * 8) = v;
        }
}

// ---------------- pv ----------------
// P-read-once: grid (KS2, N/64). Block tile 64 rows x 512 cols (full D),
// 4 waves = 128-col strips, acc[4][8]. Per wave-iter 4KB P + 8KB V feed 32 MFMA.
// Each P A-frag read by exactly ONE block; V slice per chunk (512 KB) L2-resident.
// Epilogue: scale partial by 1/dsum[row] (final after qk) and atomicAdd f32
// directly into out — replaces the bf16 Opart round-trip + reduce kernel
// (~100 MB HBM saved). Device-scope f32 atomics, 8-way reuse per address.
__global__ __launch_bounds__(NTHR, 2) void pv_kernel(
    const unsigned short* __restrict__ Pblk, const unsigned short* __restrict__ Vblk,
    const float* __restrict__ dsum, float* __restrict__ out, int iters)
{
    const int tid = threadIdx.x;
    const int wv = tid >> 6, lane = tid & 63;
    const int qq = lane >> 4, l16 = lane & 15;
    const int chunk = blockIdx.x;
    const int rg = blockIdx.y;            // 64-row group
    const int kbase = chunk * iters;      // kb32 units

    f32x4 acc[4][8];
    #pragma unroll
    for (int fy = 0; fy < 4; ++fy)
        #pragma unroll
        for (int fx = 0; fx < 8; ++fx) acc[fy][fx] = (f32x4){0.f, 0.f, 0.f, 0.f};

    for (int it = 0; it < iters; ++it) {
        const int kb32 = kbase + it;
        short8 a[4], b[8];
        #pragma unroll
        for (int fy = 0; fy < 4; ++fy)
            a[fy] = *(const short8*)(Pblk + ((size_t)kb32 * 256 + rg * 4 + fy) * FRAG_SH + lane * 8);
        #pragma unroll
        for (int fx = 0; fx < 8; ++fx)
            b[fx] = *(const short8*)(Vblk + ((size_t)kb32 * 32 + wv * 8 + fx) * FRAG_SH + lane * 8);
        __builtin_amdgcn_s_setprio(1);
        #pragma unroll
        for (int fy = 0; fy < 4; ++fy)
            #pragma unroll
            for (int fx = 0; fx < 8; ++fx)
                acc[fy][fx] = __builtin_amdgcn_mfma_f32_16x16x32_bf16(a[fy], b[fx], acc[fy][fx], 0, 0, 0);
        __builtin_amdgcn_s_setprio(0);
    }

    // per-thread rows: rg*64 + fy*16 + qq*4 + ri  (16 distinct rows)
    float inv[4][4];
    #pragma unroll
    for (int fy = 0; fy < 4; ++fy)
        #pragma unroll
        for (int ri = 0; ri < 4; ++ri)
            inv[fy][ri] = 1.0f / dsum[rg * 64 + fy * 16 + qq * 4 + ri];

    #pragma unroll
    for (int fy = 0; fy < 4; ++fy)
        #pragma unroll
        for (int ri = 0; ri < 4; ++ri) {
            const int row = rg * 64 + fy * 16 + qq * 4 + ri;
            #pragma unroll
            for (int fx = 0; fx < 8; ++fx) {
                const int col = wv * 128 + fx * 16 + l16;
                atomicAdd(out + (size_t)row * D + col, acc[fy][fx][ri] * inv[fy][ri]);
            }
        }
}

extern "C" void kernel_launch(void* const* d_in, const int* in_sizes, int n_in,
                              void* d_out, int out_size, void* d_ws, size_t ws_size,
                              hipStream_t stream) {
    const float* q     = (const float*)d_in[0];
    const float* hist  = (const float*)d_in[1];
    const float* times = (const float*)d_in[2];
    const float* w1    = (const float*)d_in[3];
    const float* b1    = (const float*)d_in[4];
    const float* w2    = (const float*)d_in[5];
    const float* b2    = (const float*)d_in[6];
    float* out = (float*)d_out;

    // ws: Vblk 4M | Pblk 32M | dsum 64K | Qblk 4M | Kblk 4M
    char* base = (char*)d_ws;
    const size_t MB4 = (size_t)N * D * 2;
    unsigned short* Vblk = (unsigned short*)base;
    unsigned short* Pblk = (unsigned short*)(base + MB4);
    float* dsum          = (float*)(base + MB4 + (size_t)N * (size_t)N * 2);
    char* ob             = base + MB4 + (size_t)N * (size_t)N * 2 + 65536;
    unsigned short* Qblk = (unsigned short*)ob;
    unsigned short* Kblk = (unsigned short*)(ob + MB4);
    const int iters = (N / 32) / KS2;   // 16

    hipFuncSetAttribute((const void*)qk_kernel,
                        hipFuncAttributeMaxDynamicSharedMemorySize, SMEM_BYTES);

    prep_kernel<<<514, NTHR, 0, stream>>>(q, hist, Qblk, Kblk, Vblk, dsum, out);
    qk_kernel<<<512, NTHR, SMEM_BYTES, stream>>>(Qblk, Kblk, times, w1, b1, w2, b2, Pblk, dsum);
    pv_kernel<<<dim3(KS2, N / 64), NTHR, 0, stream>>>(Pblk, Vblk, dsum, out, iters);
}

// Round 5
// 137.112 us; speedup vs baseline: 1.2621x; 1.2621x over previous
//
#include <hip/hip_runtime.h>

#define N 4096
#define D 512
#define FRAG_SH 512            // shorts per 16x32 MFMA fragment (1 KB)
#define NTHR 256
#define SC_STRIDE 136          // qk scratch row stride in shorts (272 B)
#define SMEM_BYTES 69632       // 4 waves * 64 rows * 136 shorts * 2 B

typedef __attribute__((ext_vector_type(8))) short short8;
typedef __attribute__((ext_vector_type(4))) float f32x4;

__device__ __forceinline__ unsigned short f2bf(float f) {
    unsigned int u = __float_as_uint(f);
    u = (u + 0x7FFFu + ((u >> 16) & 1u)) >> 16;
    return (unsigned short)u;
}
__device__ __forceinline__ unsigned short f2bf_rn(float f) {
    return (unsigned short)((__float_as_uint(f) + 0x8000u) >> 16);
}
__device__ __forceinline__ float bf2f(unsigned short u) {
    return __uint_as_float((unsigned)u << 16);
}

// ---------------- prep ----------------
// blocks [0,128): Q 32-row tile -> Qblk (A-frag-linear, pre-scaled 1/sqrt(D))
// blocks [128,256): hist 32-row tile -> Kblk (B-frag) + Vblk (B-frag)
// blocks [256,258): zero dsum
__global__ __launch_bounds__(NTHR) void prep_kernel(
    const float* __restrict__ q, const float* __restrict__ hist,
    unsigned short* __restrict__ Qblk, unsigned short* __restrict__ Kblk,
    unsigned short* __restrict__ Vblk, float* __restrict__ dsum)
{
    __shared__ unsigned short smem[32 * 512];
    const int bid = blockIdx.x, tid = threadIdx.x;
    if (bid >= 256) {
        int z = (bid - 256) * NTHR + tid;       // 0..511
        #pragma unroll
        for (int j = 0; j < 8; ++j) dsum[z * 8 + j] = 0.f;
        return;
    }
    const bool isQ = bid < 128;
    const int t = isQ ? bid : bid - 128;
    const float* src = isQ ? q : hist;
    const float scale = isQ ? 0.04419417382415922f : 1.0f;

    #pragma unroll
    for (int k = 0; k < 16; ++k) {
        int idx = tid + k * 256;
        int row = idx >> 7;
        int c4  = (idx & 127) << 2;
        float4 v = *(const float4*)(src + (size_t)(t * 32 + row) * D + c4);
        ushort4 o;
        o.x = f2bf(v.x * scale); o.y = f2bf(v.y * scale);
        o.z = f2bf(v.z * scale); o.w = f2bf(v.w * scale);
        *(ushort4*)(smem + row * 512 + c4) = o;
    }
    __syncthreads();

    unsigned short* ABdst = isQ ? Qblk : Kblk;
    #pragma unroll
    for (int k = 0; k < 8; ++k) {
        int s = tid + k * 256;
        int fl = s >> 6, ln = s & 63;
        int dk = fl >> 1, rbl = fl & 1;
        int l16 = ln & 15, qq = ln >> 4;
        short8 v = *(const short8*)(smem + (rbl * 16 + l16) * 512 + dk * 32 + qq * 8);
        *(short8*)(ABdst + ((size_t)dk * 256 + t * 2 + rbl) * FRAG_SH + ln * 8) = v;
    }
    if (!isQ) {
        #pragma unroll
        for (int k = 0; k < 8; ++k) {
            int s = tid + k * 256;
            int db = s >> 6, ln = s & 63;
            int l16 = ln & 15, qq = ln >> 4;
            unsigned short tmp[8];
            #pragma unroll
            for (int j = 0; j < 8; ++j)
                tmp[j] = smem[(qq * 8 + j) * 512 + db * 16 + l16];
            *(short8*)(Vblk + ((size_t)t * 32 + db) * FRAG_SH + ln * 8) = *(const short8*)tmp;
        }
    }
}

// ---------------- qk ----------------
// 512 blocks: rg = bid>>4 (128-row group), cg XCD-affine (256-col group).
// 4 waves, wave tile 64x128 (acc 4x8); K-loop is a 2-deep register ping-pong:
// loads for dk+1 issue BEFORE the MFMA cluster for dk (issue-early, static
// buffers fa0/fb0,fa1/fb1 — no runtime-indexed arrays, rule #20). L2 load
// latency (~300cy) hides under the 32-MFMA cluster. setprio around MFMA only.
__global__ __launch_bounds__(NTHR, 2) void qk_kernel(
    const unsigned short* __restrict__ Qblk, const unsigned short* __restrict__ Kblk,
    const float* __restrict__ times,
    const float* __restrict__ w1, const float* __restrict__ b1,
    const float* __restrict__ w2, const float* __restrict__ b2,
    unsigned short* __restrict__ Pblk, float* __restrict__ dsum)
{
    extern __shared__ unsigned short smem[];
    const int tid = threadIdx.x, bid = blockIdx.x;
    const int wv = tid >> 6, lane = tid & 63;
    const int qq = lane >> 4, l16 = lane & 15;
    const int wy = wv >> 1, wx = wv & 1;
    const int cg = ((bid & 7) << 1) | ((bid >> 3) & 1);  // XCD-affine col group
    const int rg = bid >> 4;

    f32x4 acc[4][8];
    #pragma unroll
    for (int fy = 0; fy < 4; ++fy)
        #pragma unroll
        for (int fx = 0; fx < 8; ++fx) acc[fy][fx] = (f32x4){0.f, 0.f, 0.f, 0.f};

    const size_t DKSTEP = (size_t)256 * FRAG_SH;   // shorts per dk step
    const unsigned short* qptr = Qblk + (size_t)(rg * 8 + wy * 4) * FRAG_SH + lane * 8;
    const unsigned short* kptr = Kblk + (size_t)(cg * 16 + wx * 8) * FRAG_SH + lane * 8;

    short8 fa0[4], fb0[8], fa1[4], fb1[8];
    #pragma unroll
    for (int fy = 0; fy < 4; ++fy) fa0[fy] = *(const short8*)(qptr + fy * FRAG_SH);
    #pragma unroll
    for (int fx = 0; fx < 8; ++fx) fb0[fx] = *(const short8*)(kptr + fx * FRAG_SH);

    #pragma unroll
    for (int dk = 0; dk < 16; dk += 2) {
        const unsigned short* q1 = qptr + (size_t)(dk + 1) * DKSTEP;
        const unsigned short* k1 = kptr + (size_t)(dk + 1) * DKSTEP;
        #pragma unroll
        for (int fy = 0; fy < 4; ++fy) fa1[fy] = *(const short8*)(q1 + fy * FRAG_SH);
        #pragma unroll
        for (int fx = 0; fx < 8; ++fx) fb1[fx] = *(const short8*)(k1 + fx * FRAG_SH);
        __builtin_amdgcn_s_setprio(1);
        #pragma unroll
        for (int fy = 0; fy < 4; ++fy)
            #pragma unroll
            for (int fx = 0; fx < 8; ++fx)
                acc[fy][fx] = __builtin_amdgcn_mfma_f32_16x16x32_bf16(fa0[fy], fb0[fx], acc[fy][fx], 0, 0, 0);
        __builtin_amdgcn_s_setprio(0);
        if (dk + 2 < 16) {
            const unsigned short* q2 = qptr + (size_t)(dk + 2) * DKSTEP;
            const unsigned short* k2 = kptr + (size_t)(dk + 2) * DKSTEP;
            #pragma unroll
            for (int fy = 0; fy < 4; ++fy) fa0[fy] = *(const short8*)(q2 + fy * FRAG_SH);
            #pragma unroll
            for (int fx = 0; fx < 8; ++fx) fb0[fx] = *(const short8*)(k2 + fx * FRAG_SH);
        }
        __builtin_amdgcn_s_setprio(1);
        #pragma unroll
        for (int fy = 0; fy < 4; ++fy)
            #pragma unroll
            for (int fx = 0; fx < 8; ++fx)
                acc[fy][fx] = __builtin_amdgcn_mfma_f32_16x16x32_bf16(fa1[fy], fb1[fx], acc[fy][fx], 0, 0, 0);
        __builtin_amdgcn_s_setprio(0);
    }

    float w1v[8], b1v[8], w2v[8];
    #pragma unroll
    for (int k = 0; k < 8; ++k) { w1v[k] = w1[k]; b1v[k] = b1[k]; w2v[k] = w2[k]; }
    const float b2v = b2[0];
    bool fast = true;
    #pragma unroll
    for (int k = 0; k < 8; ++k) fast = fast && (b1v[k] == 0.0f);
    float C1 = 0.0f;
    #pragma unroll
    for (int k = 0; k < 8; ++k) C1 += w2v[k] * fmaxf(w1v[k], 0.0f);

    const int rowbase = rg * 128 + wy * 64;
    const int colbase = cg * 256 + wx * 128;
    float tcol[8];
    #pragma unroll
    for (int fx = 0; fx < 8; ++fx) tcol[fx] = times[colbase + fx * 16 + l16];
    float trow[16];
    #pragma unroll
    for (int fy = 0; fy < 4; ++fy)
        #pragma unroll
        for (int ri = 0; ri < 4; ++ri)
            trow[fy * 4 + ri] = times[rowbase + fy * 16 + qq * 4 + ri];

    unsigned short* sc = smem + wv * (64 * SC_STRIDE);   // wave-private 64x136
    #pragma unroll
    for (int fy = 0; fy < 4; ++fy) {
        #pragma unroll
        for (int ri = 0; ri < 4; ++ri) {
            const float tq = trow[fy * 4 + ri];
            float se = 0.f;
            #pragma unroll
            for (int fx = 0; fx < 8; ++fx) {
                float td = fabsf(tq - tcol[fx]);
                float a = fmaf(td, C1, b2v);
                if (!fast) {
                    a = b2v;
                    #pragma unroll
                    for (int k = 0; k < 8; ++k)
                        a += w2v[k] * fmaxf(fmaf(td, w1v[k], b1v[k]), 0.f);
                }
                float twt = __builtin_amdgcn_rcpf(1.0f + __expf(-a));
                float e = __expf(acc[fy][fx][ri] * twt);   // 1/sqrt(D) folded into Q
                se += e;
                sc[(fy * 16 + qq * 4 + ri) * SC_STRIDE + fx * 16 + l16] = f2bf_rn(e);
            }
            se += __shfl_xor(se, 1);
            se += __shfl_xor(se, 2);
            se += __shfl_xor(se, 4);
            se += __shfl_xor(se, 8);
            if (l16 == 0) atomicAdd(dsum + rowbase + fy * 16 + qq * 4 + ri, se);
        }
    }
    #pragma unroll
    for (int fy = 0; fy < 4; ++fy)
        #pragma unroll
        for (int kb2 = 0; kb2 < 4; ++kb2) {
            short8 v = *(const short8*)(sc + (fy * 16 + l16) * SC_STRIDE + kb2 * 32 + qq * 8);
            size_t fidx = (size_t)(cg * 8 + wx * 4 + kb2) * 256 + (rg * 8 + wy * 4 + fy);
            *(short8*)(Pblk + fidx * FRAG_SH + lane * 8) = v;
        }
}

// ---------------- pv ----------------
// P-read-once: grid (KS2, N/(FY*16)). Block tile FY*16 rows x 512 cols,
// 4 waves = 128-col strips, acc[FY][8]. Same 2-deep register ping-pong as qk:
// P loads (HBM, ~600-900cy) and V loads (L2) for it+1 issue before the MFMA
// cluster for it. Partials to Opart bf16; reduce kernel sums (R2-verified).
template<int FY>
__global__ __launch_bounds__(NTHR, 2) void pv_kernel(
    const unsigned short* __restrict__ Pblk, const unsigned short* __restrict__ Vblk,
    unsigned short* __restrict__ Opart, int iters)
{
    const int tid = threadIdx.x;
    const int wv = tid >> 6, lane = tid & 63;
    const int qq = lane >> 4, l16 = lane & 15;
    const int chunk = blockIdx.x;
    const int rg = blockIdx.y;            // (FY*16)-row group
    const int kbase = chunk * iters;      // kb32 units

    f32x4 acc[FY][8];
    #pragma unroll
    for (int fy = 0; fy < FY; ++fy)
        #pragma unroll
        for (int fx = 0; fx < 8; ++fx) acc[fy][fx] = (f32x4){0.f, 0.f, 0.f, 0.f};

    const size_t PSTEP = (size_t)256 * FRAG_SH;   // shorts per kb32 in P
    const size_t VSTEP = (size_t)32 * FRAG_SH;    // shorts per kb32 in V
    const unsigned short* pb = Pblk + ((size_t)kbase * 256 + rg * FY) * FRAG_SH + lane * 8;
    const unsigned short* vb = Vblk + ((size_t)kbase * 32 + wv * 8) * FRAG_SH + lane * 8;

    short8 a0[FY], b0[8], a1[FY], b1[8];
    #pragma unroll
    for (int fy = 0; fy < FY; ++fy) a0[fy] = *(const short8*)(pb + fy * FRAG_SH);
    #pragma unroll
    for (int fx = 0; fx < 8; ++fx) b0[fx] = *(const short8*)(vb + fx * FRAG_SH);

    for (int it = 0; it < iters; it += 2) {    // iters is even (16/32/64)
        const unsigned short* p1 = pb + (size_t)(it + 1) * PSTEP;
        const unsigned short* v1 = vb + (size_t)(it + 1) * VSTEP;
        #pragma unroll
        for (int fy = 0; fy < FY; ++fy) a1[fy] = *(const short8*)(p1 + fy * FRAG_SH);
        #pragma unroll
        for (int fx = 0; fx < 8; ++fx) b1[fx] = *(const short8*)(v1 + fx * FRAG_SH);
        __builtin_amdgcn_s_setprio(1);
        #pragma unroll
        for (int fy = 0; fy < FY; ++fy)
            #pragma unroll
            for (int fx = 0; fx < 8; ++fx)
                acc[fy][fx] = __builtin_amdgcn_mfma_f32_16x16x32_bf16(a0[fy], b0[fx], acc[fy][fx], 0, 0, 0);
        __builtin_amdgcn_s_setprio(0);
        const int nx = (it + 2 < iters) ? (it + 2) : it;   // clamp (harmless reload at tail)
        const unsigned short* p2 = pb + (size_t)nx * PSTEP;
        const unsigned short* v2 = vb + (size_t)nx * VSTEP;
        #pragma unroll
        for (int fy = 0; fy < FY; ++fy) a0[fy] = *(const short8*)(p2 + fy * FRAG_SH);
        #pragma unroll
        for (int fx = 0; fx < 8; ++fx) b0[fx] = *(const short8*)(v2 + fx * FRAG_SH);
        __builtin_amdgcn_s_setprio(1);
        #pragma unroll
        for (int fy = 0; fy < FY; ++fy)
            #pragma unroll
            for (int fx = 0; fx < 8; ++fx)
                acc[fy][fx] = __builtin_amdgcn_mfma_f32_16x16x32_bf16(a1[fy], b1[fx], acc[fy][fx], 0, 0, 0);
        __builtin_amdgcn_s_setprio(0);
    }

    unsigned short* ob = Opart + (size_t)chunk * N * D;
    #pragma unroll
    for (int fy = 0; fy < FY; ++fy)
        #pragma unroll
        for (int ri = 0; ri < 4; ++ri) {
            const int row = rg * (FY * 16) + fy * 16 + qq * 4 + ri;
            #pragma unroll
            for (int fx = 0; fx < 8; ++fx) {
                const int col = wv * 128 + fx * 16 + l16;
                ob[(size_t)row * D + col] = f2bf_rn(acc[fy][fx][ri]);
            }
        }
}

// ---------------- reduce ----------------
// 16B loads (short8): 8 bf16/thread/chunk; grid (N*D/8)/NTHR = 1024 blocks.
__global__ __launch_bounds__(NTHR) void reduce_kernel(
    const unsigned short* __restrict__ Opart, const float* __restrict__ dsum,
    float* __restrict__ out, int KS2)
{
    int i = blockIdx.x * NTHR + threadIdx.x;   // short8 index
    int row = i >> 6;                          // D/8 = 64 short8 per row
    float inv = 1.0f / dsum[row];
    float acc[8] = {0.f, 0.f, 0.f, 0.f, 0.f, 0.f, 0.f, 0.f};
    for (int c = 0; c < KS2; ++c) {
        short8 u = ((const short8*)(Opart + (size_t)c * N * D))[i];
        #pragma unroll
        for (int j = 0; j < 8; ++j) acc[j] += bf2f((unsigned short)u[j]);
    }
    float4 o0 = {acc[0] * inv, acc[1] * inv, acc[2] * inv, acc[3] * inv};
    float4 o1 = {acc[4] * inv, acc[5] * inv, acc[6] * inv, acc[7] * inv};
    ((float4*)out)[i * 2 + 0] = o0;
    ((float4*)out)[i * 2 + 1] = o1;
}

extern "C" void kernel_launch(void* const* d_in, const int* in_sizes, int n_in,
                              void* d_out, int out_size, void* d_ws, size_t ws_size,
                              hipStream_t stream) {
    const float* q     = (const float*)d_in[0];
    const float* hist  = (const float*)d_in[1];
    const float* times = (const float*)d_in[2];
    const float* w1    = (const float*)d_in[3];
    const float* b1    = (const float*)d_in[4];
    const float* w2    = (const float*)d_in[5];
    const float* b2    = (const float*)d_in[6];
    float* out = (float*)d_out;

    // ws: Vblk 4M | Pblk 32M | dsum 64K | Qblk 4M | Kblk 4M (Opart aliases Qblk)
    char* base = (char*)d_ws;
    const size_t MB4 = (size_t)N * D * 2;
    unsigned short* Vblk = (unsigned short*)base;
    unsigned short* Pblk = (unsigned short*)(base + MB4);
    float* dsum          = (float*)(base + MB4 + (size_t)N * (size_t)N * 2);
    char* ob             = base + MB4 + (size_t)N * (size_t)N * 2 + 65536;
    unsigned short* Qblk = (unsigned short*)ob;
    unsigned short* Kblk = (unsigned short*)(ob + MB4);
    unsigned short* Opart = (unsigned short*)ob;       // pv/reduce never read Q/K
    const size_t fixed = (size_t)(ob - base);
    const int KS2 = (ws_size >= fixed + 8 * MB4) ? 8 :
                    (ws_size >= fixed + 4 * MB4) ? 4 : 2;
    const int iters = (N / 32) / KS2;

    (void)hipFuncSetAttribute((const void*)qk_kernel,
                        hipFuncAttributeMaxDynamicSharedMemorySize, SMEM_BYTES);

    prep_kernel<<<258, NTHR, 0, stream>>>(q, hist, Qblk, Kblk, Vblk, dsum);
    qk_kernel<<<512, NTHR, SMEM_BYTES, stream>>>(Qblk, Kblk, times, w1, b1, w2, b2, Pblk, dsum);
    if (KS2 == 8) {
        pv_kernel<4><<<dim3(KS2, N / 64), NTHR, 0, stream>>>(Pblk, Vblk, Opart, iters);
    } else {
        pv_kernel<2><<<dim3(KS2, N / 32), NTHR, 0, stream>>>(Pblk, Vblk, Opart, iters);
    }
    reduce_kernel<<<(N * D / 8) / NTHR, NTHR, 0, stream>>>(Opart, dsum, out, KS2);
}

// Round 11
// 132.493 us; speedup vs baseline: 1.3061x; 1.0349x over previous
//
#include <hip/hip_runtime.h>

#define N 4096
#define D 512
#define FRAG_SH 512            // shorts per 16x32 MFMA fragment (1 KB)
#define NTHR 256
#define SC_STRIDE 136          // qk scratch row stride in shorts (272 B)
#define SMEM_BYTES 69632       // max(2x24KB staging, 4 waves * 64 * 136 * 2B)
#define BUF_SH 12288           // shorts per staging buffer (24 KB)

typedef __attribute__((ext_vector_type(8))) short short8;
typedef __attribute__((ext_vector_type(4))) float f32x4;
typedef const __attribute__((address_space(1))) unsigned int* gptr_t;
typedef __attribute__((address_space(3))) unsigned int* lptr_t;

__device__ __forceinline__ unsigned short f2bf(float f) {
    unsigned int u = __float_as_uint(f);
    u = (u + 0x7FFFu + ((u >> 16) & 1u)) >> 16;
    return (unsigned short)u;
}
__device__ __forceinline__ unsigned short f2bf_rn(float f) {
    return (unsigned short)((__float_as_uint(f) + 0x8000u) >> 16);
}
__device__ __forceinline__ float bf2f(unsigned short u) {
    return __uint_as_float((unsigned)u << 16);
}

// ---------------- prep ----------------
// blocks [0,128): Q 32-row tile -> Qblk (A-frag-linear, pre-scaled 1/sqrt(D))
// blocks [128,256): hist 32-row tile -> Kblk (B-frag) + Vblk (B-frag)
// blocks [256,258): zero dsum
__global__ __launch_bounds__(NTHR) void prep_kernel(
    const float* __restrict__ q, const float* __restrict__ hist,
    unsigned short* __restrict__ Qblk, unsigned short* __restrict__ Kblk,
    unsigned short* __restrict__ Vblk, float* __restrict__ dsum)
{
    __shared__ unsigned short smem[32 * 512];
    const int bid = blockIdx.x, tid = threadIdx.x;
    if (bid >= 256) {
        int z = (bid - 256) * NTHR + tid;       // 0..511
        #pragma unroll
        for (int j = 0; j < 8; ++j) dsum[z * 8 + j] = 0.f;
        return;
    }
    const bool isQ = bid < 128;
    const int t = isQ ? bid : bid - 128;
    const float* src = isQ ? q : hist;
    const float scale = isQ ? 0.04419417382415922f : 1.0f;

    #pragma unroll
    for (int k = 0; k < 16; ++k) {
        int idx = tid + k * 256;
        int row = idx >> 7;
        int c4  = (idx & 127) << 2;
        float4 v = *(const float4*)(src + (size_t)(t * 32 + row) * D + c4);
        ushort4 o;
        o.x = f2bf(v.x * scale); o.y = f2bf(v.y * scale);
        o.z = f2bf(v.z * scale); o.w = f2bf(v.w * scale);
        *(ushort4*)(smem + row * 512 + c4) = o;
    }
    __syncthreads();

    unsigned short* ABdst = isQ ? Qblk : Kblk;
    #pragma unroll
    for (int k = 0; k < 8; ++k) {
        int s = tid + k * 256;
        int fl = s >> 6, ln = s & 63;
        int dk = fl >> 1, rbl = fl & 1;
        int l16 = ln & 15, qq = ln >> 4;
        short8 v = *(const short8*)(smem + (rbl * 16 + l16) * 512 + dk * 32 + qq * 8);
        *(short8*)(ABdst + ((size_t)dk * 256 + t * 2 + rbl) * FRAG_SH + ln * 8) = v;
    }
    if (!isQ) {
        #pragma unroll
        for (int k = 0; k < 8; ++k) {
            int s = tid + k * 256;
            int db = s >> 6, ln = s & 63;
            int l16 = ln & 15, qq = ln >> 4;
            unsigned short tmp[8];
            #pragma unroll
            for (int j = 0; j < 8; ++j)
                tmp[j] = smem[(qq * 8 + j) * 512 + db * 16 + l16];
            *(short8*)(Vblk + ((size_t)t * 32 + db) * FRAG_SH + ln * 8) = *(const short8*)tmp;
        }
    }
}

// ---------------- qk ----------------
// 512 blocks: rg = bid>>4 (128-row group), cg XCD-affine (256-col group).
// 4 waves, wave tile 64x128 (acc 4x8). Main loop = m97-style 2-phase:
// per dk, stage next 24KB tile (8 A-frags + 16 B-frags, contiguous in
// frag-linear layout) via global_load_lds (zero VGPR cost for in-flight
// data — fixes R5's VGPR-cap load serialization), consume current buffer
// via conflict-free ds_read_b128, one __syncthreads per iter (implicit
// vmcnt drain). Staging LDS (48KB) aliases epilogue scratch (68KB) —
// separated by the final barrier.
__global__ __launch_bounds__(NTHR, 2) void qk_kernel(
    const unsigned short* __restrict__ Qblk, const unsigned short* __restrict__ Kblk,
    const float* __restrict__ times,
    const float* __restrict__ w1, const float* __restrict__ b1,
    const float* __restrict__ w2, const float* __restrict__ b2,
    unsigned short* __restrict__ Pblk, float* __restrict__ dsum)
{
    extern __shared__ unsigned short smem[];
    const int tid = threadIdx.x, bid = blockIdx.x;
    const int wv = tid >> 6, lane = tid & 63;
    const int qq = lane >> 4, l16 = lane & 15;
    const int wy = wv >> 1, wx = wv & 1;
    const int cg = ((bid & 7) << 1) | ((bid >> 3) & 1);  // XCD-affine col group
    const int rg = bid >> 4;

    f32x4 acc[4][8];
    #pragma unroll
    for (int fy = 0; fy < 4; ++fy)
        #pragma unroll
        for (int fx = 0; fx < 8; ++fx) acc[fy][fx] = (f32x4){0.f, 0.f, 0.f, 0.f};

    // stage dk's 24 segs of 1KB into buf: wave wv owns segs wv*6..wv*6+5.
    // segs 0..7 = A-frags rg*8+s; segs 8..23 = B-frags cg*16+(s-8).
    // LDS dst is wave-uniform (HW adds lane*16); global src is per-lane.
    auto stage = [&](int dk, int buf) {
        unsigned short* ldsb = smem + buf * BUF_SH;
        #pragma unroll
        for (int j = 0; j < 6; ++j) {
            const int s = wv * 6 + j;
            const unsigned short* g = (s < 8)
                ? (Qblk + ((size_t)dk * 256 + rg * 8 + s) * FRAG_SH + lane * 8)
                : (Kblk + ((size_t)dk * 256 + cg * 16 + (s - 8)) * FRAG_SH + lane * 8);
            __builtin_amdgcn_global_load_lds(
                (gptr_t)g, (lptr_t)(ldsb + s * FRAG_SH), 16, 0, 0);
        }
    };
    auto compute = [&](int buf) {
        const unsigned short* bufc = smem + buf * BUF_SH;
        short8 fa[4], fb[8];
        #pragma unroll
        for (int fy = 0; fy < 4; ++fy)
            fa[fy] = *(const short8*)(bufc + (wy * 4 + fy) * FRAG_SH + lane * 8);
        #pragma unroll
        for (int fx = 0; fx < 8; ++fx)
            fb[fx] = *(const short8*)(bufc + (8 + wx * 8 + fx) * FRAG_SH + lane * 8);
        #pragma unroll
        for (int fy = 0; fy < 4; ++fy)
            #pragma unroll
            for (int fx = 0; fx < 8; ++fx)
                acc[fy][fx] = __builtin_amdgcn_mfma_f32_16x16x32_bf16(fa[fy], fb[fx], acc[fy][fx], 0, 0, 0);
    };

    stage(0, 0);
    __syncthreads();                       // drains vmcnt: buf0 ready
    #pragma unroll 1
    for (int dk = 0; dk < 16; dk += 2) {
        stage(dk + 1, 1);                  // dk+1 <= 15 always
        compute(0);
        __syncthreads();                   // buf1 staged; all done reading buf0
        if (dk + 2 < 16) stage(dk + 2, 0);
        compute(1);
        __syncthreads();                   // buf0 staged; all done reading buf1
    }

    float w1v[8], b1v[8], w2v[8];
    #pragma unroll
    for (int k = 0; k < 8; ++k) { w1v[k] = w1[k]; b1v[k] = b1[k]; w2v[k] = w2[k]; }
    const float b2v = b2[0];
    bool fast = true;
    #pragma unroll
    for (int k = 0; k < 8; ++k) fast = fast && (b1v[k] == 0.0f);
    float C1 = 0.0f;
    #pragma unroll
    for (int k = 0; k < 8; ++k) C1 += w2v[k] * fmaxf(w1v[k], 0.0f);

    const int rowbase = rg * 128 + wy * 64;
    const int colbase = cg * 256 + wx * 128;
    float tcol[8];
    #pragma unroll
    for (int fx = 0; fx < 8; ++fx) tcol[fx] = times[colbase + fx * 16 + l16];
    float trow[16];
    #pragma unroll
    for (int fy = 0; fy < 4; ++fy)
        #pragma unroll
        for (int ri = 0; ri < 4; ++ri)
            trow[fy * 4 + ri] = times[rowbase + fy * 16 + qq * 4 + ri];

    unsigned short* sc = smem + wv * (64 * SC_STRIDE);   // wave-private 64x136
    #pragma unroll
    for (int fy = 0; fy < 4; ++fy) {
        #pragma unroll
        for (int ri = 0; ri < 4; ++ri) {
            const float tq = trow[fy * 4 + ri];
            float se = 0.f;
            #pragma unroll
            for (int fx = 0; fx < 8; ++fx) {
                float td = fabsf(tq - tcol[fx]);
                float a = fmaf(td, C1, b2v);
                if (!fast) {
                    a = b2v;
                    #pragma unroll
                    for (int k = 0; k < 8; ++k)
                        a += w2v[k] * fmaxf(fmaf(td, w1v[k], b1v[k]), 0.f);
                }
                float twt = __builtin_amdgcn_rcpf(1.0f + __expf(-a));
                float e = __expf(acc[fy][fx][ri] * twt);   // 1/sqrt(D) folded into Q
                se += e;
                sc[(fy * 16 + qq * 4 + ri) * SC_STRIDE + fx * 16 + l16] = f2bf_rn(e);
            }
            se += __shfl_xor(se, 1);
            se += __shfl_xor(se, 2);
            se += __shfl_xor(se, 4);
            se += __shfl_xor(se, 8);
            if (l16 == 0) atomicAdd(dsum + rowbase + fy * 16 + qq * 4 + ri, se);
        }
    }
    #pragma unroll
    for (int fy = 0; fy < 4; ++fy)
        #pragma unroll
        for (int kb2 = 0; kb2 < 4; ++kb2) {
            short8 v = *(const short8*)(sc + (fy * 16 + l16) * SC_STRIDE + kb2 * 32 + qq * 8);
            size_t fidx = (size_t)(cg * 8 + wx * 4 + kb2) * 256 + (rg * 8 + wy * 4 + fy);
            *(short8*)(Pblk + fidx * FRAG_SH + lane * 8) = v;
        }
}

// ---------------- pv ----------------
// P-read-once: grid (KS2, N/(FY*16)). Block tile FY*16 rows x 512 cols,
// 4 waves = 128-col strips, acc[FY][8] (R2-benched simple loop; VGPR 96).
// Each P A-frag read by exactly ONE block; V slice per chunk L2-resident.
// Barrier-free, no LDS. setprio: independent-wave regime (m191 case).
template<int FY>
__global__ __launch_bounds__(NTHR, 2) void pv_kernel(
    const unsigned short* __restrict__ Pblk, const unsigned short* __restrict__ Vblk,
    unsigned short* __restrict__ Opart, int iters)
{
    const int tid = threadIdx.x;
    const int wv = tid >> 6, lane = tid & 63;
    const int qq = lane >> 4, l16 = lane & 15;
    const int chunk = blockIdx.x;
    const int rg = blockIdx.y;            // (FY*16)-row group
    const int kbase = chunk * iters;      // kb32 units

    f32x4 acc[FY][8];
    #pragma unroll
    for (int fy = 0; fy < FY; ++fy)
        #pragma unroll
        for (int fx = 0; fx < 8; ++fx) acc[fy][fx] = (f32x4){0.f, 0.f, 0.f, 0.f};

    for (int it = 0; it < iters; ++it) {
        const int kb32 = kbase + it;
        short8 a[FY], b[8];
        #pragma unroll
        for (int fy = 0; fy < FY; ++fy)
            a[fy] = *(const short8*)(Pblk + ((size_t)kb32 * 256 + rg * FY + fy) * FRAG_SH + lane * 8);
        #pragma unroll
        for (int fx = 0; fx < 8; ++fx)
            b[fx] = *(const short8*)(Vblk + ((size_t)kb32 * 32 + wv * 8 + fx) * FRAG_SH + lane * 8);
        __builtin_amdgcn_s_setprio(1);
        #pragma unroll
        for (int fy = 0; fy < FY; ++fy)
            #pragma unroll
            for (int fx = 0; fx < 8; ++fx)
                acc[fy][fx] = __builtin_amdgcn_mfma_f32_16x16x32_bf16(a[fy], b[fx], acc[fy][fx], 0, 0, 0);
        __builtin_amdgcn_s_setprio(0);
    }

    unsigned short* ob = Opart + (size_t)chunk * N * D;
    #pragma unroll
    for (int fy = 0; fy < FY; ++fy)
        #pragma unroll
        for (int ri = 0; ri < 4; ++ri) {
            const int row = rg * (FY * 16) + fy * 16 + qq * 4 + ri;
            #pragma unroll
            for (int fx = 0; fx < 8; ++fx) {
                const int col = wv * 128 + fx * 16 + l16;
                ob[(size_t)row * D + col] = f2bf_rn(acc[fy][fx][ri]);
            }
        }
}

// ---------------- reduce ----------------
// 16B loads (short8): 8 bf16/thread/chunk; grid (N*D/8)/NTHR = 1024 blocks.
__global__ __launch_bounds__(NTHR) void reduce_kernel(
    const unsigned short* __restrict__ Opart, const float* __restrict__ dsum,
    float* __restrict__ out, int KS2)
{
    int i = blockIdx.x * NTHR + threadIdx.x;   // short8 index
    int row = i >> 6;                          // D/8 = 64 short8 per row
    float inv = 1.0f / dsum[row];
    float acc[8] = {0.f, 0.f, 0.f, 0.f, 0.f, 0.f, 0.f, 0.f};
    for (int c = 0; c < KS2; ++c) {
        short8 u = ((const short8*)(Opart + (size_t)c * N * D))[i];
        #pragma unroll
        for (int j = 0; j < 8; ++j) acc[j] += bf2f((unsigned short)u[j]);
    }
    float4 o0 = {acc[0] * inv, acc[1] * inv, acc[2] * inv, acc[3] * inv};
    float4 o1 = {acc[4] * inv, acc[5] * inv, acc[6] * inv, acc[7] * inv};
    ((float4*)out)[i * 2 + 0] = o0;
    ((float4*)out)[i * 2 + 1] = o1;
}

extern "C" void kernel_launch(void* const* d_in, const int* in_sizes, int n_in,
                              void* d_out, int out_size, void* d_ws, size_t ws_size,
                              hipStream_t stream) {
    const float* q     = (const float*)d_in[0];
    const float* hist  = (const float*)d_in[1];
    const float* times = (const float*)d_in[2];
    const float* w1    = (const float*)d_in[3];
    const float* b1    = (const float*)d_in[4];
    const float* w2    = (const float*)d_in[5];
    const float* b2    = (const float*)d_in[6];
    float* out = (float*)d_out;

    // ws: Vblk 4M | Pblk 32M | dsum 64K | Qblk 4M | Kblk 4M (Opart aliases Qblk)
    char* base = (char*)d_ws;
    const size_t MB4 = (size_t)N * D * 2;
    unsigned short* Vblk = (unsigned short*)base;
    unsigned short* Pblk = (unsigned short*)(base + MB4);
    float* dsum          = (float*)(base + MB4 + (size_t)N * (size_t)N * 2);
    char* ob             = base + MB4 + (size_t)N * (size_t)N * 2 + 65536;
    unsigned short* Qblk = (unsigned short*)ob;
    unsigned short* Kblk = (unsigned short*)(ob + MB4);
    unsigned short* Opart = (unsigned short*)ob;       // pv/reduce never read Q/K
    const size_t fixed = (size_t)(ob - base);
    const int KS2 = (ws_size >= fixed + 8 * MB4) ? 8 :
                    (ws_size >= fixed + 4 * MB4) ? 4 : 2;
    const int iters = (N / 32) / KS2;

    (void)hipFuncSetAttribute((const void*)qk_kernel,
                        hipFuncAttributeMaxDynamicSharedMemorySize, SMEM_BYTES);

    prep_kernel<<<258, NTHR, 0, stream>>>(q, hist, Qblk, Kblk, Vblk, dsum);
    qk_kernel<<<512, NTHR, SMEM_BYTES, stream>>>(Qblk, Kblk, times, w1, b1, w2, b2, Pblk, dsum);
    if (KS2 == 8) {
        pv_kernel<4><<<dim3(KS2, N / 64), NTHR, 0, stream>>>(Pblk, Vblk, Opart, iters);
    } else {
        pv_kernel<2><<<dim3(KS2, N / 32), NTHR, 0, stream>>>(Pblk, Vblk, Opart, iters);
    }
    reduce_kernel<<<(N * D / 8) / NTHR, NTHR, 0, stream>>>(Opart, dsum, out, KS2);
}

// Round 12
// 132.437 us; speedup vs baseline: 1.3067x; 1.0004x over previous
//
#include <hip/hip_runtime.h>

#define N 4096
#define D 512
#define FRAG_SH 512            // shorts per 16x32 MFMA fragment (1 KB)
#define NTHR 256
#define SC_STRIDE 136          // qk scratch row stride in shorts (272 B)
#define SMEM_BYTES 69632       // max(2x24KB staging, 4 waves * 64 * 136 * 2B)
#define BUF_SH 12288           // shorts per staging buffer (24 KB)

typedef __attribute__((ext_vector_type(8))) short short8;
typedef __attribute__((ext_vector_type(4))) float f32x4;
typedef const __attribute__((address_space(1))) unsigned int* gptr_t;
typedef __attribute__((address_space(3))) unsigned int* lptr_t;

__device__ __forceinline__ unsigned short f2bf(float f) {
    unsigned int u = __float_as_uint(f);
    u = (u + 0x7FFFu + ((u >> 16) & 1u)) >> 16;
    return (unsigned short)u;
}
__device__ __forceinline__ unsigned short f2bf_rn(float f) {
    return (unsigned short)((__float_as_uint(f) + 0x8000u) >> 16);
}
__device__ __forceinline__ float bf2f(unsigned short u) {
    return __uint_as_float((unsigned)u << 16);
}

// ---------------- prep ----------------
// blocks [0,128): Q 32-row tile -> Qblk (A-frag-linear, pre-scaled 1/sqrt(D))
// blocks [128,256): hist 32-row tile -> Kblk (B-frag) + Vblk (B-frag)
// blocks [256,258): zero dsum
__global__ __launch_bounds__(NTHR) void prep_kernel(
    const float* __restrict__ q, const float* __restrict__ hist,
    unsigned short* __restrict__ Qblk, unsigned short* __restrict__ Kblk,
    unsigned short* __restrict__ Vblk, float* __restrict__ dsum)
{
    __shared__ unsigned short smem[32 * 512];
    const int bid = blockIdx.x, tid = threadIdx.x;
    if (bid >= 256) {
        int z = (bid - 256) * NTHR + tid;       // 0..511
        #pragma unroll
        for (int j = 0; j < 8; ++j) dsum[z * 8 + j] = 0.f;
        return;
    }
    const bool isQ = bid < 128;
    const int t = isQ ? bid : bid - 128;
    const float* src = isQ ? q : hist;
    const float scale = isQ ? 0.04419417382415922f : 1.0f;

    #pragma unroll
    for (int k = 0; k < 16; ++k) {
        int idx = tid + k * 256;
        int row = idx >> 7;
        int c4  = (idx & 127) << 2;
        float4 v = *(const float4*)(src + (size_t)(t * 32 + row) * D + c4);
        ushort4 o;
        o.x = f2bf(v.x * scale); o.y = f2bf(v.y * scale);
        o.z = f2bf(v.z * scale); o.w = f2bf(v.w * scale);
        *(ushort4*)(smem + row * 512 + c4) = o;
    }
    __syncthreads();

    unsigned short* ABdst = isQ ? Qblk : Kblk;
    #pragma unroll
    for (int k = 0; k < 8; ++k) {
        int s = tid + k * 256;
        int fl = s >> 6, ln = s & 63;
        int dk = fl >> 1, rbl = fl & 1;
        int l16 = ln & 15, qq = ln >> 4;
        short8 v = *(const short8*)(smem + (rbl * 16 + l16) * 512 + dk * 32 + qq * 8);
        *(short8*)(ABdst + ((size_t)dk * 256 + t * 2 + rbl) * FRAG_SH + ln * 8) = v;
    }
    if (!isQ) {
        #pragma unroll
        for (int k = 0; k < 8; ++k) {
            int s = tid + k * 256;
            int db = s >> 6, ln = s & 63;
            int l16 = ln & 15, qq = ln >> 4;
            unsigned short tmp[8];
            #pragma unroll
            for (int j = 0; j < 8; ++j)
                tmp[j] = smem[(qq * 8 + j) * 512 + db * 16 + l16];
            *(short8*)(Vblk + ((size_t)t * 32 + db) * FRAG_SH + ln * 8) = *(const short8*)tmp;
        }
    }
}

// ---------------- qk ----------------
// 512 blocks: rg = bid>>4 (128-row group), cg XCD-affine (256-col group).
// 4 waves, wave tile 64x128 (acc 4x8). Main loop = 2-phase global_load_lds
// staging with COUNTED vmcnt (T4, m201/m218): each wave issues exactly 6 DMA
// per stage; "vmcnt(6) + raw s_barrier" proves the PREVIOUS tile landed while
// the next tile's 6 loads stay in flight across the barrier — never drain to
// 0 in the loop (vs __syncthreads' implicit vmcnt(0), the m97 ~20% stall).
// barrier-2 after compute keeps stage(dk+2) from overwriting a live buffer.
// Last iter waits vmcnt(0) so epilogue scratch (aliases staging LDS) is safe.
__global__ __launch_bounds__(NTHR, 2) void qk_kernel(
    const unsigned short* __restrict__ Qblk, const unsigned short* __restrict__ Kblk,
    const float* __restrict__ times,
    const float* __restrict__ w1, const float* __restrict__ b1,
    const float* __restrict__ w2, const float* __restrict__ b2,
    unsigned short* __restrict__ Pblk, float* __restrict__ dsum)
{
    extern __shared__ unsigned short smem[];
    const int tid = threadIdx.x, bid = blockIdx.x;
    const int wv = tid >> 6, lane = tid & 63;
    const int qq = lane >> 4, l16 = lane & 15;
    const int wy = wv >> 1, wx = wv & 1;
    const int cg = ((bid & 7) << 1) | ((bid >> 3) & 1);  // XCD-affine col group
    const int rg = bid >> 4;

    f32x4 acc[4][8];
    #pragma unroll
    for (int fy = 0; fy < 4; ++fy)
        #pragma unroll
        for (int fx = 0; fx < 8; ++fx) acc[fy][fx] = (f32x4){0.f, 0.f, 0.f, 0.f};

    // stage dk's 24 segs of 1KB into buf: wave wv owns segs wv*6..wv*6+5.
    // segs 0..7 = A-frags rg*8+s; segs 8..23 = B-frags cg*16+(s-8).
    // LDS dst is wave-uniform (HW adds lane*16); global src is per-lane.
    auto stage = [&](int dk, int buf) {
        unsigned short* ldsb = smem + buf * BUF_SH;
        #pragma unroll
        for (int j = 0; j < 6; ++j) {
            const int s = wv * 6 + j;
            const unsigned short* g = (s < 8)
                ? (Qblk + ((size_t)dk * 256 + rg * 8 + s) * FRAG_SH + lane * 8)
                : (Kblk + ((size_t)dk * 256 + cg * 16 + (s - 8)) * FRAG_SH + lane * 8);
            __builtin_amdgcn_global_load_lds(
                (gptr_t)g, (lptr_t)(ldsb + s * FRAG_SH), 16, 0, 0);
        }
    };
    auto compute = [&](int buf) {
        const unsigned short* bufc = smem + buf * BUF_SH;
        short8 fa[4], fb[8];
        #pragma unroll
        for (int fy = 0; fy < 4; ++fy)
            fa[fy] = *(const short8*)(bufc + (wy * 4 + fy) * FRAG_SH + lane * 8);
        #pragma unroll
        for (int fx = 0; fx < 8; ++fx)
            fb[fx] = *(const short8*)(bufc + (8 + wx * 8 + fx) * FRAG_SH + lane * 8);
        #pragma unroll
        for (int fy = 0; fy < 4; ++fy)
            #pragma unroll
            for (int fx = 0; fx < 8; ++fx)
                acc[fy][fx] = __builtin_amdgcn_mfma_f32_16x16x32_bf16(fa[fy], fb[fx], acc[fy][fx], 0, 0, 0);
    };

    stage(0, 0);
    #pragma unroll 1
    for (int dk = 0; dk < 16; ++dk) {
        if (dk + 1 < 16) {
            stage(dk + 1, (dk + 1) & 1);
            // oldest 6 (= stage(dk)) done; stage(dk+1)'s 6 stay in flight
            asm volatile("s_waitcnt vmcnt(6)" ::: "memory");
        } else {
            asm volatile("s_waitcnt vmcnt(0)" ::: "memory");
        }
        __builtin_amdgcn_s_barrier();      // all waves: tile dk fully in LDS
        compute(dk & 1);
        __builtin_amdgcn_s_barrier();      // all waves done reading buf dk&1
    }

    float w1v[8], b1v[8], w2v[8];
    #pragma unroll
    for (int k = 0; k < 8; ++k) { w1v[k] = w1[k]; b1v[k] = b1[k]; w2v[k] = w2[k]; }
    const float b2v = b2[0];
    bool fast = true;
    #pragma unroll
    for (int k = 0; k < 8; ++k) fast = fast && (b1v[k] == 0.0f);
    float C1 = 0.0f;
    #pragma unroll
    for (int k = 0; k < 8; ++k) C1 += w2v[k] * fmaxf(w1v[k], 0.0f);

    const int rowbase = rg * 128 + wy * 64;
    const int colbase = cg * 256 + wx * 128;
    float tcol[8];
    #pragma unroll
    for (int fx = 0; fx < 8; ++fx) tcol[fx] = times[colbase + fx * 16 + l16];
    float trow[16];
    #pragma unroll
    for (int fy = 0; fy < 4; ++fy)
        #pragma unroll
        for (int ri = 0; ri < 4; ++ri)
            trow[fy * 4 + ri] = times[rowbase + fy * 16 + qq * 4 + ri];

    unsigned short* sc = smem + wv * (64 * SC_STRIDE);   // wave-private 64x136
    #pragma unroll
    for (int fy = 0; fy < 4; ++fy) {
        #pragma unroll
        for (int ri = 0; ri < 4; ++ri) {
            const float tq = trow[fy * 4 + ri];
            float se = 0.f;
            #pragma unroll
            for (int fx = 0; fx < 8; ++fx) {
                float td = fabsf(tq - tcol[fx]);
                float a = fmaf(td, C1, b2v);
                if (!fast) {
                    a = b2v;
                    #pragma unroll
                    for (int k = 0; k < 8; ++k)
                        a += w2v[k] * fmaxf(fmaf(td, w1v[k], b1v[k]), 0.f);
                }
                float twt = __builtin_amdgcn_rcpf(1.0f + __expf(-a));
                float e = __expf(acc[fy][fx][ri] * twt);   // 1/sqrt(D) folded into Q
                se += e;
                sc[(fy * 16 + qq * 4 + ri) * SC_STRIDE + fx * 16 + l16] = f2bf_rn(e);
            }
            se += __shfl_xor(se, 1);
            se += __shfl_xor(se, 2);
            se += __shfl_xor(se, 4);
            se += __shfl_xor(se, 8);
            if (l16 == 0) atomicAdd(dsum + rowbase + fy * 16 + qq * 4 + ri, se);
        }
    }
    #pragma unroll
    for (int fy = 0; fy < 4; ++fy)
        #pragma unroll
        for (int kb2 = 0; kb2 < 4; ++kb2) {
            short8 v = *(const short8*)(sc + (fy * 16 + l16) * SC_STRIDE + kb2 * 32 + qq * 8);
            size_t fidx = (size_t)(cg * 8 + wx * 4 + kb2) * 256 + (rg * 8 + wy * 4 + fy);
            *(short8*)(Pblk + fidx * FRAG_SH + lane * 8) = v;
        }
}

// ---------------- pv ----------------
// P-read-once: grid (KS2, N/(FY*16)). Block tile FY*16 rows x 512 cols,
// 4 waves = 128-col strips, acc[FY][8] (R2-benched simple loop; VGPR 96).
// Each P A-frag read by exactly ONE block; V slice per chunk L2-resident.
// Barrier-free, no LDS. setprio: independent-wave regime (m191 case).
template<int FY>
__global__ __launch_bounds__(NTHR, 2) void pv_kernel(
    const unsigned short* __restrict__ Pblk, const unsigned short* __restrict__ Vblk,
    unsigned short* __restrict__ Opart, int iters)
{
    const int tid = threadIdx.x;
    const int wv = tid >> 6, lane = tid & 63;
    const int qq = lane >> 4, l16 = lane & 15;
    const int chunk = blockIdx.x;
    const int rg = blockIdx.y;            // (FY*16)-row group
    const int kbase = chunk * iters;      // kb32 units

    f32x4 acc[FY][8];
    #pragma unroll
    for (int fy = 0; fy < FY; ++fy)
        #pragma unroll
        for (int fx = 0; fx < 8; ++fx) acc[fy][fx] = (f32x4){0.f, 0.f, 0.f, 0.f};

    for (int it = 0; it < iters; ++it) {
        const int kb32 = kbase + it;
        short8 a[FY], b[8];
        #pragma unroll
        for (int fy = 0; fy < FY; ++fy)
            a[fy] = *(const short8*)(Pblk + ((size_t)kb32 * 256 + rg * FY + fy) * FRAG_SH + lane * 8);
        #pragma unroll
        for (int fx = 0; fx < 8; ++fx)
            b[fx] = *(const short8*)(Vblk + ((size_t)kb32 * 32 + wv * 8 + fx) * FRAG_SH + lane * 8);
        __builtin_amdgcn_s_setprio(1);
        #pragma unroll
        for (int fy = 0; fy < FY; ++fy)
            #pragma unroll
            for (int fx = 0; fx < 8; ++fx)
                acc[fy][fx] = __builtin_amdgcn_mfma_f32_16x16x32_bf16(a[fy], b[fx], acc[fy][fx], 0, 0, 0);
        __builtin_amdgcn_s_setprio(0);
    }

    unsigned short* ob = Opart + (size_t)chunk * N * D;
    #pragma unroll
    for (int fy = 0; fy < FY; ++fy)
        #pragma unroll
        for (int ri = 0; ri < 4; ++ri) {
            const int row = rg * (FY * 16) + fy * 16 + qq * 4 + ri;
            #pragma unroll
            for (int fx = 0; fx < 8; ++fx) {
                const int col = wv * 128 + fx * 16 + l16;
                ob[(size_t)row * D + col] = f2bf_rn(acc[fy][fx][ri]);
            }
        }
}

// ---------------- reduce ----------------
// 16B loads (short8): 8 bf16/thread/chunk; grid (N*D/8)/NTHR = 1024 blocks.
__global__ __launch_bounds__(NTHR) void reduce_kernel(
    const unsigned short* __restrict__ Opart, const float* __restrict__ dsum,
    float* __restrict__ out, int KS2)
{
    int i = blockIdx.x * NTHR + threadIdx.x;   // short8 index
    int row = i >> 6;                          // D/8 = 64 short8 per row
    float inv = 1.0f / dsum[row];
    float acc[8] = {0.f, 0.f, 0.f, 0.f, 0.f, 0.f, 0.f, 0.f};
    for (int c = 0; c < KS2; ++c) {
        short8 u = ((const short8*)(Opart + (size_t)c * N * D))[i];
        #pragma unroll
        for (int j = 0; j < 8; ++j) acc[j] += bf2f((unsigned short)u[j]);
    }
    float4 o0 = {acc[0] * inv, acc[1] * inv, acc[2] * inv, acc[3] * inv};
    float4 o1 = {acc[4] * inv, acc[5] * inv, acc[6] * inv, acc[7] * inv};
    ((float4*)out)[i * 2 + 0] = o0;
    ((float4*)out)[i * 2 + 1] = o1;
}

extern "C" void kernel_launch(void* const* d_in, const int* in_sizes, int n_in,
                              void* d_out, int out_size, void* d_ws, size_t ws_size,
                              hipStream_t stream) {
    const float* q     = (const float*)d_in[0];
    const float* hist  = (const float*)d_in[1];
    const float* times = (const float*)d_in[2];
    const float* w1    = (const float*)d_in[3];
    const float* b1    = (const float*)d_in[4];
    const float* w2    = (const float*)d_in[5];
    const float* b2    = (const float*)d_in[6];
    float* out = (float*)d_out;

    // ws: Vblk 4M | Pblk 32M | dsum 64K | Qblk 4M | Kblk 4M (Opart aliases Qblk)
    char* base = (char*)d_ws;
    const size_t MB4 = (size_t)N * D * 2;
    unsigned short* Vblk = (unsigned short*)base;
    unsigned short* Pblk = (unsigned short*)(base + MB4);
    float* dsum          = (float*)(base + MB4 + (size_t)N * (size_t)N * 2);
    char* ob             = base + MB4 + (size_t)N * (size_t)N * 2 + 65536;
    unsigned short* Qblk = (unsigned short*)ob;
    unsigned short* Kblk = (unsigned short*)(ob + MB4);
    unsigned short* Opart = (unsigned short*)ob;       // pv/reduce never read Q/K
    const size_t fixed = (size_t)(ob - base);
    const int KS2 = (ws_size >= fixed + 8 * MB4) ? 8 :
                    (ws_size >= fixed + 4 * MB4) ? 4 : 2;
    const int iters = (N / 32) / KS2;

    (void)hipFuncSetAttribute((const void*)qk_kernel,
                        hipFuncAttributeMaxDynamicSharedMemorySize, SMEM_BYTES);

    prep_kernel<<<258, NTHR, 0, stream>>>(q, hist, Qblk, Kblk, Vblk, dsum);
    qk_kernel<<<512, NTHR, SMEM_BYTES, stream>>>(Qblk, Kblk, times, w1, b1, w2, b2, Pblk, dsum);
    if (KS2 == 8) {
        pv_kernel<4><<<dim3(KS2, N / 64), NTHR, 0, stream>>>(Pblk, Vblk, Opart, iters);
    } else {
        pv_kernel<2><<<dim3(KS2, N / 32), NTHR, 0, stream>>>(Pblk, Vblk, Opart, iters);
    }
    reduce_kernel<<<(N * D / 8) / NTHR, NTHR, 0, stream>>>(Opart, dsum, out, KS2);
}